// Round 6
// baseline (308.255 us; speedup 1.0000x reference)
//
#include <hip/hip_runtime.h>
#include <hip/hip_bf16.h>

#define BB 8
#define TT 4
#define NN 4096
#define UU 64
#define EE 65536
#define BN (BB*NN)   // 32768
#define CAP 64
#define NEG 0.2f

// ws layout (float offsets); hp/es/ed ping-pong by t parity
#define OFF_XT   0                      // 12*BN  (t,f,row)
#define OFF_HP0  (12*BN)                // BN*64 row-major h'
#define OFF_HP1  (OFF_HP0 + 64*BN)
#define OFF_ES0  (OFF_HP1 + 64*BN)     // BN
#define OFF_ES1  (OFF_ES0 + BN)
#define OFF_ED0  (OFF_ES1 + BN)
#define OFF_ED1  (OFF_ED0 + BN)
#define OFF_CNT  (OFF_ED1 + BN)        // NN ints
#define OFF_SLOT (OFF_CNT + NN)        // NN*CAP ints (ends ~19.9 MB)

// XCD-aware block remap: pin batch i to XCD i (R2: FETCH 42.9->7.4 MB; keep).
__device__ __forceinline__ int xcd_remap(int bid) {
  return ((bid & 7) << 6) | (bid >> 3);
}

// readlane helpers: VALU op -> SGPR broadcast (NOT the DS pipe).
__device__ __forceinline__ float rlf(float v, int l) {
  return __int_as_float(__builtin_amdgcn_readlane(__float_as_int(v), l));
}
__device__ __forceinline__ int rli(int v, int l) {
  return __builtin_amdgcn_readlane(v, l);
}

__global__ __launch_bounds__(256) void k_conv_x(const float* x, float* xT) {
  int i = blockIdx.x * 256 + threadIdx.x;     // < 12*BN
  int r = i & (BN - 1);
  int tf = i >> 15;
  int t = tf / 3, f = tf - 3 * t;
  int b = r >> 12, n = r & (NN - 1);
  xT[i] = x[(((b * TT + t) * NN + n) * 3) + f];
}

__global__ __launch_bounds__(256) void k_fill(const int* src, const int* dst,
                                              int* cnt, int* slot) {
  int i = blockIdx.x * 256 + threadIdx.x;
  if (i < EE) {
    int d = dst[i];
    int p = atomicAdd(&cnt[d], 1);
    if (p < CAP) slot[d * CAP + p] = src[i];
  } else if (i < EE + NN) {
    int n = i - EE;
    int p = atomicAdd(&cnt[n], 1);
    if (p < CAP) slot[n * CAP + p] = n;
  }
}

// GAT at t=0 (h == 0): h' = x_0 @ gat_W[64:67]; es/ed. Writes buffer 0.
__global__ __launch_bounds__(512) void k_gat0(float* ws, const float* gW,
                                              const float* as_, const float* ad_) {
  const float* xT = ws + OFF_XT;
  float* hp = ws + OFF_HP0;
  float* es = ws + OFF_ES0;
  float* ed = ws + OFF_ED0;
  int wave = __builtin_amdgcn_readfirstlane(threadIdx.x >> 6);
  int lane = threadIdx.x & 63;
  int lb = xcd_remap(blockIdx.x);
  int row = lb * 64 + lane;
  int u0 = wave * 8;
  float acc[8];
#pragma unroll
  for (int j = 0; j < 8; ++j) acc[j] = 0.f;
#pragma unroll
  for (int k = 0; k < 3; ++k) {
    float ck = xT[k * BN + row];   // t=0
#pragma unroll
    for (int j = 0; j < 8; ++j) acc[j] += ck * gW[(64 + k) * 64 + u0 + j];
  }
  float esa = 0.f, eda = 0.f;
#pragma unroll
  for (int j = 0; j < 8; ++j) {
    esa += acc[j] * as_[u0 + j];
    eda += acc[j] * ad_[u0 + j];
  }
  float4* o = (float4*)(hp + (size_t)row * 64 + u0);
  o[0] = make_float4(acc[0], acc[1], acc[2], acc[3]);
  o[1] = make_float4(acc[4], acc[5], acc[6], acc[7]);
  __shared__ float esL[8][64], edL[8][64];
  esL[wave][lane] = esa;
  edL[wave][lane] = eda;
  __syncthreads();
  if (wave == 0) {
    float s = 0.f;
#pragma unroll
    for (int w = 0; w < 8; ++w) s += esL[w][lane];
    es[row] = s;
  } else if (wave == 1) {
    float s = 0.f;
#pragma unroll
    for (int w = 0; w < 8; ++w) s += edL[w][lane];
    ed[row] = s;
  }
}

// Fused step: attn(t) -> GRU(t) -> [GAT(t+1) | out head].
// R6: ZERO-LDS wave-local structure. 512 thr, 8 waves, 64 rows/block,
// grid = BN/64 = 512. Wave w owns rows 8w..8w+7; lane = u.
//  - s, r*s, h live in REGISTERS (sv[8]/rs[8]/h[8], lane=u).
//  - Cross-lane matmul broadcast s[r][k] via v_readlane (VALU pipe, SGPR
//    operand into v_fmac) -- the per-CU DS pipe was the ~60us wall (R0-R5
//    all saturated it via ds_read/ds_bpermute; SQ_LDS_BANK_CONFLICT=0
//    hid it because reads were conflict-free but throughput-bound).
//  - P1 gather: slot index + weight broadcast via readlane -> SGPR addr/operand.
//  - Softmax max-reduce DELETED: |e| <= ~8 analytically, exp can't overflow;
//    exp(e)/sum(exp(e)) == exp(e-m)/sum(exp(e-m)).
//  - Remaining DS: sum butterfly (6/row) + es/ed butterflies (12/row).
__global__ __launch_bounds__(512, 4) void k_step(
    float* ws, const float* gb, const float* g1W, const float* g1b,
    const float* g2W, const float* g2b, const float* gW, const float* as_,
    const float* ad_, const float* oW, const float* ob, float* out, int t,
    int last) {
  const float* xT = ws + OFF_XT;
  int pr = t & 1;
  const float* hpR = ws + (pr ? OFF_HP1 : OFF_HP0);
  const float* esR = ws + (pr ? OFF_ES1 : OFF_ES0);
  const float* edR = ws + (pr ? OFF_ED1 : OFF_ED0);
  float* hpW = ws + (pr ? OFF_HP0 : OFF_HP1);
  float* esW = ws + (pr ? OFF_ES0 : OFF_ES1);
  float* edW = ws + (pr ? OFF_ED0 : OFF_ED1);
  const int* cnt = (const int*)(ws + OFF_CNT);
  const int* slot = (const int*)(ws + OFF_SLOT);

  int wave = __builtin_amdgcn_readfirstlane(threadIdx.x >> 6);  // 0..7
  int lane = threadIdx.x & 63;
  int lb = xcd_remap(blockIdx.x);
  int rowbase = lb * 64;
  int b = rowbase / NN;
  int nbase = rowbase - b * NN;
  int r0 = wave * 8;
  float gbv = gb[lane];   // lane = u throughout

  // ---- P1: attention, 8 rows per wave; sv[r] = s[row r0+r][u=lane] ----
  float sv[8];
#pragma unroll 1
  for (int rr = 0; rr < 8; ++rr) {
    int n = nbase + r0 + rr;
    int deg = min(cnt[n], CAP);
    float edv = edR[b * NN + n];
    int sl = (lane < deg) ? slot[n * CAP + lane] : 0;
    float e = (lane < deg) ? (esR[b * NN + sl] + edv) : -1e30f;
    e = e > 0.f ? e : NEG * e;          // -1e30 -> -2e29 -> exp = 0
    float w = __expf(e);                 // no max-subtract (|e| <= ~8)
    float dsum = w;
#pragma unroll
    for (int o = 32; o >= 1; o >>= 1) dsum += __shfl_xor(dsum, o, 64);
    w *= 1.f / dsum;
    float acc = 0.f;
#pragma unroll 1
    for (int i0 = 0; i0 < deg; i0 += 8) {
#pragma unroll
      for (int j = 0; j < 8; ++j) {
        int idx = rli(sl, i0 + j);       // SGPR slot index
        float wj = rlf(w, i0 + j);       // SGPR weight (0 for i>=deg)
        acc += wj * hpR[(size_t)(b * NN + idx) * 64 + lane];
      }
    }
    sv[rr] = acc + gbv;
  }

  // uniform x values for this wave's 8 rows (scalar loads)
  float b1r = g1b[lane];
  float b1u = g1b[64 + lane];
  float b2v = g2b[lane];

  // ---- Phase A: r/u gate pre-activations for 8 rows (lane = u') ----
  float aR[8], aU[8];
#pragma unroll
  for (int r = 0; r < 8; ++r) { aR[r] = 0.f; aU[r] = 0.f; }
#pragma unroll
  for (int k3 = 0; k3 < 3; ++k3) {
    float wl = g1W[k3 * 128 + lane];
    float wh = g1W[k3 * 128 + 64 + lane];
#pragma unroll
    for (int r = 0; r < 8; ++r) {
      float xk = xT[(t * 3 + k3) * BN + rowbase + r0 + r];  // uniform
      aR[r] += xk * wl;
      aU[r] += xk * wh;
    }
  }
#pragma unroll 4
  for (int k = 0; k < 64; ++k) {
    float wl = g1W[(3 + k) * 128 + lane];
    float wh = g1W[(3 + k) * 128 + 64 + lane];
#pragma unroll
    for (int r = 0; r < 8; ++r) {
      float sk = rlf(sv[r], k);          // VALU broadcast, SGPR operand
      aR[r] += sk * wl;
      aU[r] += sk * wh;
    }
  }
  float rs[8], ug[8];
#pragma unroll
  for (int r = 0; r < 8; ++r) {
    float rg = 1.f / (1.f + __expf(-(aR[r] + b1r)));
    rs[r] = rg * sv[r];
    ug[r] = 1.f / (1.f + __expf(-(aU[r] + b1u)));
  }

  // ---- Phase B: candidate + state update (all in regs) ----
  float aC[8];
#pragma unroll
  for (int r = 0; r < 8; ++r) aC[r] = 0.f;
#pragma unroll
  for (int k3 = 0; k3 < 3; ++k3) {
    float wc = g2W[k3 * 64 + lane];
#pragma unroll
    for (int r = 0; r < 8; ++r) {
      float xk = xT[(t * 3 + k3) * BN + rowbase + r0 + r];
      aC[r] += xk * wc;
    }
  }
#pragma unroll 4
  for (int k = 0; k < 64; ++k) {
    float wc = g2W[(3 + k) * 64 + lane];
#pragma unroll
    for (int r = 0; r < 8; ++r) {
      float rk = rlf(rs[r], k);
      aC[r] += rk * wc;
    }
  }
  float h8[8];
#pragma unroll
  for (int r = 0; r < 8; ++r) {
    float z = aC[r] + b2v;
    float c = 1.f - 2.f / (__expf(2.f * z) + 1.f);
    h8[r] = ug[r] * sv[r] + (1.f - ug[r]) * c;
  }

  if (!last) {
    // ---- P5: GAT for step t+1 on own rows' h (in regs) ----
    float aG[8];
#pragma unroll
    for (int r = 0; r < 8; ++r) aG[r] = 0.f;
#pragma unroll
    for (int k3 = 0; k3 < 3; ++k3) {
      float wg = gW[(64 + k3) * 64 + lane];
#pragma unroll
      for (int r = 0; r < 8; ++r) {
        float xk = xT[((t + 1) * 3 + k3) * BN + rowbase + r0 + r];
        aG[r] += xk * wg;
      }
    }
#pragma unroll 4
    for (int k = 0; k < 64; ++k) {
      float wg = gW[k * 64 + lane];
#pragma unroll
      for (int r = 0; r < 8; ++r) {
        float hk = rlf(h8[r], k);
        aG[r] += hk * wg;
      }
    }
    float asv = as_[lane], adv = ad_[lane];
#pragma unroll 1
    for (int r = 0; r < 8; ++r) {
      int row = rowbase + r0 + r;
      hpW[(size_t)row * 64 + lane] = aG[r];
      float pe = aG[r] * asv;
      float pd = aG[r] * adv;
#pragma unroll
      for (int o = 32; o >= 1; o >>= 1) {
        pe += __shfl_xor(pe, o, 64);
        pd += __shfl_xor(pd, o, 64);
      }
      if (lane == 0) {
        esW[row] = pe;
        edW[row] = pd;
      }
    }
  } else {
    // ---- P5': output head out[row,:] = h . oW + ob ----
    float w0 = oW[lane * 3 + 0];
    float w1 = oW[lane * 3 + 1];
    float w2 = oW[lane * 3 + 2];
    float ob0 = ob[0], ob1 = ob[1], ob2 = ob[2];
#pragma unroll 1
    for (int r = 0; r < 8; ++r) {
      int row = rowbase + r0 + r;
      float o0 = h8[r] * w0;
      float o1 = h8[r] * w1;
      float o2 = h8[r] * w2;
#pragma unroll
      for (int o = 32; o >= 1; o >>= 1) {
        o0 += __shfl_xor(o0, o, 64);
        o1 += __shfl_xor(o1, o, 64);
        o2 += __shfl_xor(o2, o, 64);
      }
      if (lane == 0) {
        out[(size_t)row * 3 + 0] = o0 + ob0;
        out[(size_t)row * 3 + 1] = o1 + ob1;
        out[(size_t)row * 3 + 2] = o2 + ob2;
      }
    }
  }
}

extern "C" void kernel_launch(void* const* d_in, const int* in_sizes, int n_in,
                              void* d_out, int out_size, void* d_ws, size_t ws_size,
                              hipStream_t stream) {
  const float* x = (const float*)d_in[0];
  const int* src = (const int*)d_in[1];
  const int* dst = (const int*)d_in[2];
  const float* gatW = (const float*)d_in[3];
  const float* asrc = (const float*)d_in[4];
  const float* adst = (const float*)d_in[5];
  const float* gatb = (const float*)d_in[6];
  const float* g1W = (const float*)d_in[7];
  const float* g1b = (const float*)d_in[8];
  const float* g2W = (const float*)d_in[9];
  const float* g2b = (const float*)d_in[10];
  const float* oW = (const float*)d_in[11];
  const float* ob = (const float*)d_in[12];
  float* ws = (float*)d_ws;
  float* out = (float*)d_out;

  hipMemsetAsync(ws + OFF_CNT, 0, NN * sizeof(int), stream);
  k_conv_x<<<(12 * BN) / 256, 256, 0, stream>>>(x, ws + OFF_XT);
  k_fill<<<(EE + NN) / 256, 256, 0, stream>>>(src, dst, (int*)(ws + OFF_CNT),
                                              (int*)(ws + OFF_SLOT));
  k_gat0<<<BN / 64, 512, 0, stream>>>(ws, gatW, asrc, adst);
  for (int t = 0; t < TT; ++t) {
    k_step<<<BN / 64, 512, 0, stream>>>(ws, gatb, g1W, g1b, g2W, g2b, gatW,
                                        asrc, adst, oW, ob, out, t,
                                        t == TT - 1 ? 1 : 0);
  }
}

// Round 7
// 204.330 us; speedup vs baseline: 1.5086x; 1.5086x over previous
//
#include <hip/hip_runtime.h>
#include <hip/hip_bf16.h>

#define BB 8
#define TT 4
#define NN 4096
#define UU 64
#define EE 65536
#define BN (BB*NN)   // 32768
#define CAP 64
#define NEG 0.2f

// ws layout (float offsets); hp/es/ed ping-pong by t parity
#define OFF_XT   0                      // 12*BN  (t,f,row)
#define OFF_HP0  (12*BN)                // BN*64 row-major h'
#define OFF_HP1  (OFF_HP0 + 64*BN)
#define OFF_ES0  (OFF_HP1 + 64*BN)     // BN
#define OFF_ES1  (OFF_ES0 + BN)
#define OFF_ED0  (OFF_ES1 + BN)
#define OFF_ED1  (OFF_ED0 + BN)
#define OFF_CNT  (OFF_ED1 + BN)        // NN ints
#define OFF_SLOT (OFF_CNT + NN)        // NN*CAP ints
#define OFF_W    (OFF_SLOT + NN*CAP)   // f16 weight panels (frag-ordered), 16B aligned

// f16 panel offsets (in halfs). Element ((n*NKK+kk)*64+lane)*8+j holds
// W[k = kk*32 + (lane>>4)*8 + j][col = n*16 + (lane&15)] (zero-padded).
#define PW1 0          // G1: [s|x|0](96) @ g1W -> 128 cols; 8n x 3kk
#define PW2 12288      // G2: [rs|x|0](96) @ g2W -> 64 cols; 4n x 3kk
#define PW3 18432      // G3: [h|x'|0](96) @ gW  -> 64 cols; 4n x 3kk
#define PW4 24576      // G4: h(64) @ oW -> 16 cols (3 used); 1n x 2kk
#define NPANEL 25600

typedef _Float16 f16_t;
typedef _Float16 f16x8 __attribute__((ext_vector_type(8)));
typedef float f32x4 __attribute__((ext_vector_type(4)));

// XCD-aware block remap: pin batch i to XCD i (R2: FETCH 42.9->7.4 MB; keep).
__device__ __forceinline__ int xcd_remap(int bid) {
  return ((bid & 7) << 6) | (bid >> 3);
}

// readlane helpers: VALU broadcast -> SGPR (P1 gather).
__device__ __forceinline__ float rlf(float v, int l) {
  return __int_as_float(__builtin_amdgcn_readlane(__float_as_int(v), l));
}
__device__ __forceinline__ int rli(int v, int l) {
  return __builtin_amdgcn_readlane(v, l);
}

__global__ __launch_bounds__(256) void k_conv_x(const float* x, float* xT) {
  int i = blockIdx.x * 256 + threadIdx.x;     // < 12*BN
  int r = i & (BN - 1);
  int tf = i >> 15;
  int t = tf / 3, f = tf - 3 * t;
  int b = r >> 12, n = r & (NN - 1);
  xT[i] = x[(((b * TT + t) * NN + n) * 3) + f];
}

__global__ __launch_bounds__(256) void k_fill(const int* src, const int* dst,
                                              int* cnt, int* slot) {
  int i = blockIdx.x * 256 + threadIdx.x;
  if (i < EE) {
    int d = dst[i];
    int p = atomicAdd(&cnt[d], 1);
    if (p < CAP) slot[d * CAP + p] = src[i];
  } else if (i < EE + NN) {
    int n = i - EE;
    int p = atomicAdd(&cnt[n], 1);
    if (p < CAP) slot[n * CAP + p] = n;
  }
}

// Pack f32 weights into frag-ordered f16 panels (once per launch).
__global__ __launch_bounds__(256) void k_wpack(const float* g1W, const float* g2W,
                                               const float* gW, const float* oW,
                                               f16_t* P) {
  int i = blockIdx.x * 256 + threadIdx.x;
  if (i >= NPANEL) return;
  int j = i & 7;
  int l = (i >> 3) & 63;          // panel offsets are multiples of 512 -> valid
  int kap = ((l >> 4) << 3) + j;  // k within a kk-step, 0..31
  float v = 0.f;
  if (i < PW2) {
    int r = i >> 9;               // n*3+kk
    int kk = r % 3, n = r / 3;
    int k = kk * 32 + kap, col = n * 16 + (l & 15);
    if (k < 64) v = g1W[(3 + k) * 128 + col];
    else if (k < 67) v = g1W[(k - 64) * 128 + col];
  } else if (i < PW3) {
    int r = (i - PW2) >> 9;
    int kk = r % 3, n = r / 3;
    int k = kk * 32 + kap, col = n * 16 + (l & 15);
    if (k < 64) v = g2W[(3 + k) * 64 + col];
    else if (k < 67) v = g2W[(k - 64) * 64 + col];
  } else if (i < PW4) {
    int r = (i - PW3) >> 9;
    int kk = r % 3, n = r / 3;
    int k = kk * 32 + kap, col = n * 16 + (l & 15);
    if (k < 67) v = gW[k * 64 + col];   // gat_W rows: 0..63=h, 64..66=x (identity map)
  } else {
    int kk = (i - PW4) >> 9;            // 0..1
    int k = kk * 32 + kap, col = l & 15;
    if (col < 3) v = oW[k * 3 + col];
  }
  P[i] = (f16_t)v;
}

// GAT at t=0 (h == 0): h' = x_0 @ gat_W[64:67]; es/ed. Writes buffer 0.
__global__ __launch_bounds__(512) void k_gat0(float* ws, const float* gW,
                                              const float* as_, const float* ad_) {
  const float* xT = ws + OFF_XT;
  float* hp = ws + OFF_HP0;
  float* es = ws + OFF_ES0;
  float* ed = ws + OFF_ED0;
  int wave = __builtin_amdgcn_readfirstlane(threadIdx.x >> 6);
  int lane = threadIdx.x & 63;
  int lb = xcd_remap(blockIdx.x);
  int row = lb * 64 + lane;
  int u0 = wave * 8;
  float acc[8];
#pragma unroll
  for (int j = 0; j < 8; ++j) acc[j] = 0.f;
#pragma unroll
  for (int k = 0; k < 3; ++k) {
    float ck = xT[k * BN + row];   // t=0
#pragma unroll
    for (int j = 0; j < 8; ++j) acc[j] += ck * gW[(64 + k) * 64 + u0 + j];
  }
  float esa = 0.f, eda = 0.f;
#pragma unroll
  for (int j = 0; j < 8; ++j) {
    esa += acc[j] * as_[u0 + j];
    eda += acc[j] * ad_[u0 + j];
  }
  float4* o = (float4*)(hp + (size_t)row * 64 + u0);
  o[0] = make_float4(acc[0], acc[1], acc[2], acc[3]);
  o[1] = make_float4(acc[4], acc[5], acc[6], acc[7]);
  __shared__ float esL[8][64], edL[8][64];
  esL[wave][lane] = esa;
  edL[wave][lane] = eda;
  __syncthreads();
  if (wave == 0) {
    float s = 0.f;
#pragma unroll
    for (int w = 0; w < 8; ++w) s += esL[w][lane];
    es[row] = s;
  } else if (wave == 1) {
    float s = 0.f;
#pragma unroll
    for (int w = 0; w < 8; ++w) s += edL[w][lane];
    ed[row] = s;
  }
}

// R7: P1 gather on VALU (unchanged, lane=u) -> s to LDS f16 ->
// MFMA GEMMs G1 (ru gates), G2 (candidate), G3 (next GAT) / G4 (out head).
// 512 thr, 8 waves, 64 rows/block, grid = 512.
// A-frags: ds_read_b128 from [64][104]-padded f16 tiles (row=lane&15,
// k=(lane>>4)*8+j). B-frags: 1 coalesced 16B load from pre-swizzled panel.
// C layout (HW-verified): col=lane&15, row=(lane>>4)*4+j.
__global__ __launch_bounds__(512, 4) void k_step(
    float* ws, const f16_t* P, const float* gb, const float* g1b,
    const float* g2b, const float* as_, const float* ad_,
    const float* ob, float* out, int t, int last) {
  const float* xT = ws + OFF_XT;
  int pr = t & 1;
  const float* hpR = ws + (pr ? OFF_HP1 : OFF_HP0);
  const float* esR = ws + (pr ? OFF_ES1 : OFF_ES0);
  const float* edR = ws + (pr ? OFF_ED1 : OFF_ED0);
  float* hpW = ws + (pr ? OFF_HP0 : OFF_HP1);
  float* esW = ws + (pr ? OFF_ES0 : OFF_ES1);
  float* edW = ws + (pr ? OFF_ED0 : OFF_ED1);
  const int* cnt = (const int*)(ws + OFF_CNT);
  const int* slot = (const int*)(ws + OFF_SLOT);

  int tid = threadIdx.x;
  int wave = __builtin_amdgcn_readfirstlane(tid >> 6);  // 0..7
  int lane = tid & 63;
  int lb = xcd_remap(blockIdx.x);
  int rowbase = lb * 64;
  int b = rowbase / NN;
  int nbase = rowbase - b * NN;
  int r0 = wave * 8;

  __shared__ f16_t sx[64][104];    // A-tile: [s|x|0] -> later [h|x'|0]
  __shared__ f16_t rsx[64][104];   // A-tile: [r*s|x|0]
  __shared__ f16_t ugx[64][64];    // u gate
  __shared__ float peL[2][64], pdL[2][64];

  // tail fill k=64..95 of sx,rsx = [x(t) | zeros]
  for (int i = tid; i < 64 * 32; i += 512) {
    int row = i >> 5, kq = i & 31;
    f16_t v = (f16_t)0.f;
    if (kq < 3) v = (f16_t)xT[(t * 3 + kq) * BN + rowbase + row];
    sx[row][64 + kq] = v;
    rsx[row][64 + kq] = v;
  }

  float gbv = gb[lane];   // lane = u in P1

  // ---- P1: attention, 8 rows/wave (lane=u); write s -> sx f16 ----
#pragma unroll 1
  for (int rr = 0; rr < 8; ++rr) {
    int n = nbase + r0 + rr;
    int deg = min(cnt[n], CAP);
    float edv = edR[b * NN + n];
    int sl = (lane < deg) ? slot[n * CAP + lane] : 0;
    float e = (lane < deg) ? (esR[b * NN + sl] + edv) : -1e30f;
    e = e > 0.f ? e : NEG * e;          // -1e30 -> exp = 0
    float w = __expf(e);                 // |e| <= ~8, no max-subtract needed
    float dsum = w;
#pragma unroll
    for (int o = 32; o >= 1; o >>= 1) dsum += __shfl_xor(dsum, o, 64);
    w *= 1.f / dsum;
    float acc = 0.f;
#pragma unroll 1
    for (int i0 = 0; i0 < deg; i0 += 8) {
#pragma unroll
      for (int j = 0; j < 8; ++j) {
        int idx = rli(sl, i0 + j);
        float wj = rlf(w, i0 + j);
        acc += wj * hpR[(size_t)(b * NN + idx) * 64 + lane];
      }
    }
    sx[r0 + rr][lane] = (f16_t)(acc + gbv);
  }
  __syncthreads();

  const f16x8* W1v = (const f16x8*)(P + PW1);
  const f16x8* W2v = (const f16x8*)(P + PW2);
  const f16x8* W3v = (const f16x8*)(P + PW3);
  const f16x8* W4v = (const f16x8*)(P + PW4);

  int m = wave >> 1;               // C row-tile
  int col16 = lane & 15;
  int g4 = (lane >> 4) << 2;       // C row-group offset within tile
  int rbase = m * 16 + g4;         // + j = local row
  int afrow = m * 16 + col16;      // A-frag row (row = lane&15)
  int afk = (lane >> 4) << 3;      // A-frag k offset within kk-step

  // ---- G1: [s|x] @ g1W -> 64x128 (r | u pre-activations) ----
  int nb1 = (wave & 1) * 4;
  f32x4 acc1[4] = {{0,0,0,0},{0,0,0,0},{0,0,0,0},{0,0,0,0}};
#pragma unroll
  for (int kk = 0; kk < 3; ++kk) {
    f16x8 a = *(const f16x8*)&sx[afrow][kk * 32 + afk];
#pragma unroll
    for (int nt = 0; nt < 4; ++nt) {
      f16x8 bf = W1v[((nb1 + nt) * 3 + kk) * 64 + lane];
      acc1[nt] = __builtin_amdgcn_mfma_f32_16x16x32_f16(a, bf, acc1[nt], 0, 0, 0);
    }
  }
  if ((wave & 1) == 0) {           // r half: rs -> rsx
#pragma unroll
    for (int nt = 0; nt < 4; ++nt) {
      int colR = (nb1 + nt) * 16 + col16;
      float bR = g1b[colR];
#pragma unroll
      for (int j = 0; j < 4; ++j) {
        int row = rbase + j;
        float rg = 1.f / (1.f + __expf(-(acc1[nt][j] + bR)));
        rsx[row][colR] = (f16_t)(rg * (float)sx[row][colR]);
      }
    }
  } else {                          // u half: ug -> ugx
#pragma unroll
    for (int nt = 0; nt < 4; ++nt) {
      int colU = (nb1 - 4 + nt) * 16 + col16;
      float bU = g1b[64 + colU];
#pragma unroll
      for (int j = 0; j < 4; ++j) {
        int row = rbase + j;
        float ug = 1.f / (1.f + __expf(-(acc1[nt][j] + bU)));
        ugx[row][colU] = (f16_t)ug;
      }
    }
  }
  __syncthreads();

  // ---- G2: [rs|x] @ g2W -> candidate; h update in epilogue ----
  int nb2 = (wave & 1) * 2;
  f32x4 acc2[2] = {{0,0,0,0},{0,0,0,0}};
#pragma unroll
  for (int kk = 0; kk < 3; ++kk) {
    f16x8 a = *(const f16x8*)&rsx[afrow][kk * 32 + afk];
#pragma unroll
    for (int nt = 0; nt < 2; ++nt) {
      f16x8 bf = W2v[((nb2 + nt) * 3 + kk) * 64 + lane];
      acc2[nt] = __builtin_amdgcn_mfma_f32_16x16x32_f16(a, bf, acc2[nt], 0, 0, 0);
    }
  }
#pragma unroll
  for (int nt = 0; nt < 2; ++nt) {
    int col = (nb2 + nt) * 16 + col16;
    float bC = g2b[col];
#pragma unroll
    for (int j = 0; j < 4; ++j) {
      int row = rbase + j;
      float z = acc2[nt][j] + bC;
      float c = 1.f - 2.f / (__expf(2.f * z) + 1.f);
      float ug = (float)ugx[row][col];
      float sv = (float)sx[row][col];
      sx[row][col] = (f16_t)(ug * sv + (1.f - ug) * c);   // h (owner-only RMW)
    }
  }
  if (!last && tid < 256) {        // x(t) -> x(t+1) in sx tail
    int row = tid >> 2, k3 = tid & 3;
    if (k3 < 3)
      sx[row][64 + k3] = (f16_t)xT[((t + 1) * 3 + k3) * BN + rowbase + row];
  }
  __syncthreads();

  if (!last) {
    // ---- G3: [h|x'] @ gat_W -> hp' + es/ed ----
    int nb3 = (wave & 1) * 2;
    f32x4 acc3[2] = {{0,0,0,0},{0,0,0,0}};
#pragma unroll
    for (int kk = 0; kk < 3; ++kk) {
      f16x8 a = *(const f16x8*)&sx[afrow][kk * 32 + afk];
#pragma unroll
      for (int nt = 0; nt < 2; ++nt) {
        f16x8 bf = W3v[((nb3 + nt) * 3 + kk) * 64 + lane];
        acc3[nt] = __builtin_amdgcn_mfma_f32_16x16x32_f16(a, bf, acc3[nt], 0, 0, 0);
      }
    }
    float pe[4] = {0, 0, 0, 0}, pd[4] = {0, 0, 0, 0};
#pragma unroll
    for (int nt = 0; nt < 2; ++nt) {
      int col = (nb3 + nt) * 16 + col16;
      float asv = as_[col], adv = ad_[col];
#pragma unroll
      for (int j = 0; j < 4; ++j) {
        int row = rbase + j;
        float aG = acc3[nt][j];
        hpW[(size_t)(rowbase + row) * 64 + col] = aG;
        pe[j] += aG * asv;
        pd[j] += aG * adv;
      }
    }
#pragma unroll
    for (int j = 0; j < 4; ++j) {
#pragma unroll
      for (int o = 1; o < 16; o <<= 1) {
        pe[j] += __shfl_xor(pe[j], o, 64);
        pd[j] += __shfl_xor(pd[j], o, 64);
      }
    }
    if (col16 == 0) {
#pragma unroll
      for (int j = 0; j < 4; ++j) {
        peL[wave & 1][rbase + j] = pe[j];
        pdL[wave & 1][rbase + j] = pd[j];
      }
    }
    __syncthreads();
    if (tid < 64) {
      esW[rowbase + tid] = peL[0][tid] + peL[1][tid];
    } else if (tid < 128) {
      int r_ = tid - 64;
      edW[rowbase + r_] = pdL[0][r_] + pdL[1][r_];
    }
  } else {
    // ---- G4: out = h @ oW + ob (waves 0..3, 1 tile each) ----
    if (wave < 4) {
      f32x4 acc4 = {0, 0, 0, 0};
#pragma unroll
      for (int kk = 0; kk < 2; ++kk) {
        f16x8 a = *(const f16x8*)&sx[wave * 16 + col16][kk * 32 + afk];
        f16x8 bf = W4v[kk * 64 + lane];
        acc4 = __builtin_amdgcn_mfma_f32_16x16x32_f16(a, bf, acc4, 0, 0, 0);
      }
      if (col16 < 3) {
        float obv = ob[col16];
#pragma unroll
        for (int j = 0; j < 4; ++j) {
          int row = wave * 16 + g4 + j;
          out[(size_t)(rowbase + row) * 3 + col16] = acc4[j] + obv;
        }
      }
    }
  }
}

extern "C" void kernel_launch(void* const* d_in, const int* in_sizes, int n_in,
                              void* d_out, int out_size, void* d_ws, size_t ws_size,
                              hipStream_t stream) {
  const float* x = (const float*)d_in[0];
  const int* src = (const int*)d_in[1];
  const int* dst = (const int*)d_in[2];
  const float* gatW = (const float*)d_in[3];
  const float* asrc = (const float*)d_in[4];
  const float* adst = (const float*)d_in[5];
  const float* gatb = (const float*)d_in[6];
  const float* g1W = (const float*)d_in[7];
  const float* g1b = (const float*)d_in[8];
  const float* g2W = (const float*)d_in[9];
  const float* g2b = (const float*)d_in[10];
  const float* oW = (const float*)d_in[11];
  const float* ob = (const float*)d_in[12];
  float* ws = (float*)d_ws;
  float* out = (float*)d_out;
  f16_t* P = (f16_t*)(ws + OFF_W);

  hipMemsetAsync(ws + OFF_CNT, 0, NN * sizeof(int), stream);
  k_conv_x<<<(12 * BN) / 256, 256, 0, stream>>>(x, ws + OFF_XT);
  k_fill<<<(EE + NN) / 256, 256, 0, stream>>>(src, dst, (int*)(ws + OFF_CNT),
                                              (int*)(ws + OFF_SLOT));
  k_wpack<<<(NPANEL + 255) / 256, 256, 0, stream>>>(g1W, g2W, gatW, oW, P);
  k_gat0<<<BN / 64, 512, 0, stream>>>(ws, gatW, asrc, adst);
  for (int t = 0; t < TT; ++t) {
    k_step<<<BN / 64, 512, 0, stream>>>(ws, P, gatb, g1b, g2b, asrc, adst,
                                        ob, out, t, t == TT - 1 ? 1 : 0);
  }
}

// Round 8
// 196.531 us; speedup vs baseline: 1.5685x; 1.0397x over previous
//
#include <hip/hip_runtime.h>
#include <hip/hip_bf16.h>

#define BB 8
#define TT 4
#define NN 4096
#define UU 64
#define EE 65536
#define BN (BB*NN)   // 32768
#define CAP 64
#define NEG 0.2f

// ws layout (float offsets); hp/es/ed ping-pong by t parity.
// R8: hp stored as f16 (uses half of each HP region); slot stored as u16.
#define OFF_XT   0                      // 12*BN  (t,f,row)
#define OFF_HP0  (12*BN)                // BN*64 f16 h' (region sized for f32; half used)
#define OFF_HP1  (OFF_HP0 + 64*BN)
#define OFF_ES0  (OFF_HP1 + 64*BN)     // BN
#define OFF_ES1  (OFF_ES0 + BN)
#define OFF_ED0  (OFF_ES1 + BN)
#define OFF_ED1  (OFF_ED0 + BN)
#define OFF_CNT  (OFF_ED1 + BN)        // NN ints
#define OFF_SLOT (OFF_CNT + NN)        // NN*CAP u16 (region sized for int; half used)
#define OFF_W    (OFF_SLOT + NN*CAP)   // f16 weight panels (frag-ordered), 16B aligned

// f16 panel offsets (in halfs). Element ((n*NKK+kk)*64+lane)*8+j holds
// W[k = kk*32 + (lane>>4)*8 + j][col = n*16 + (lane&15)] (zero-padded).
#define PW1 0          // G1: [s|x|0](96) @ g1W -> 128 cols; 8n x 3kk
#define PW2 12288      // G2: [rs|x|0](96) @ g2W -> 64 cols; 4n x 3kk
#define PW3 18432      // G3: [h|x'|0](96) @ gW  -> 64 cols; 4n x 3kk
#define PW4 24576      // G4: h(64) @ oW -> 16 cols (3 used); 1n x 2kk
#define NPANEL 25600

typedef _Float16 f16_t;
typedef _Float16 f16x8 __attribute__((ext_vector_type(8)));
typedef float f32x4 __attribute__((ext_vector_type(4)));

// XCD-aware block remap: pin batch i to XCD i (R2: FETCH 42.9->7.4 MB; keep).
__device__ __forceinline__ int xcd_remap(int bid) {
  return ((bid & 7) << 6) | (bid >> 3);
}

// readlane helpers: VALU broadcast -> SGPR (P1 gather).
__device__ __forceinline__ float rlf(float v, int l) {
  return __int_as_float(__builtin_amdgcn_readlane(__float_as_int(v), l));
}
__device__ __forceinline__ int rli(int v, int l) {
  return __builtin_amdgcn_readlane(v, l);
}

__global__ __launch_bounds__(256) void k_conv_x(const float* x, float* xT) {
  int i = blockIdx.x * 256 + threadIdx.x;     // < 12*BN
  int r = i & (BN - 1);
  int tf = i >> 15;
  int t = tf / 3, f = tf - 3 * t;
  int b = r >> 12, n = r & (NN - 1);
  xT[i] = x[(((b * TT + t) * NN + n) * 3) + f];
}

__global__ __launch_bounds__(256) void k_fill(const int* src, const int* dst,
                                              int* cnt, unsigned short* slot) {
  int i = blockIdx.x * 256 + threadIdx.x;
  if (i < EE) {
    int d = dst[i];
    int p = atomicAdd(&cnt[d], 1);
    if (p < CAP) slot[d * CAP + p] = (unsigned short)src[i];
  } else if (i < EE + NN) {
    int n = i - EE;
    int p = atomicAdd(&cnt[n], 1);
    if (p < CAP) slot[n * CAP + p] = (unsigned short)n;
  }
}

// Pack f32 weights into frag-ordered f16 panels (once per launch).
__global__ __launch_bounds__(256) void k_wpack(const float* g1W, const float* g2W,
                                               const float* gW, const float* oW,
                                               f16_t* P) {
  int i = blockIdx.x * 256 + threadIdx.x;
  if (i >= NPANEL) return;
  int j = i & 7;
  int l = (i >> 3) & 63;          // panel offsets are multiples of 512 -> valid
  int kap = ((l >> 4) << 3) + j;  // k within a kk-step, 0..31
  float v = 0.f;
  if (i < PW2) {
    int r = i >> 9;               // n*3+kk
    int kk = r % 3, n = r / 3;
    int k = kk * 32 + kap, col = n * 16 + (l & 15);
    if (k < 64) v = g1W[(3 + k) * 128 + col];
    else if (k < 67) v = g1W[(k - 64) * 128 + col];
  } else if (i < PW3) {
    int r = (i - PW2) >> 9;
    int kk = r % 3, n = r / 3;
    int k = kk * 32 + kap, col = n * 16 + (l & 15);
    if (k < 64) v = g2W[(3 + k) * 64 + col];
    else if (k < 67) v = g2W[(k - 64) * 64 + col];
  } else if (i < PW4) {
    int r = (i - PW3) >> 9;
    int kk = r % 3, n = r / 3;
    int k = kk * 32 + kap, col = n * 16 + (l & 15);
    if (k < 67) v = gW[k * 64 + col];   // gat_W rows: 0..63=h, 64..66=x (identity map)
  } else {
    int kk = (i - PW4) >> 9;            // 0..1
    int k = kk * 32 + kap, col = l & 15;
    if (col < 3) v = oW[k * 3 + col];
  }
  P[i] = (f16_t)v;
}

// GAT at t=0 (h == 0): h' = x_0 @ gat_W[64:67]; es/ed. Writes buffer 0 (f16 hp).
__global__ __launch_bounds__(512) void k_gat0(float* ws, const float* gW,
                                              const float* as_, const float* ad_) {
  const float* xT = ws + OFF_XT;
  f16_t* hp = (f16_t*)(ws + OFF_HP0);
  float* es = ws + OFF_ES0;
  float* ed = ws + OFF_ED0;
  int wave = __builtin_amdgcn_readfirstlane(threadIdx.x >> 6);
  int lane = threadIdx.x & 63;
  int lb = xcd_remap(blockIdx.x);
  int row = lb * 64 + lane;
  int u0 = wave * 8;
  float acc[8];
#pragma unroll
  for (int j = 0; j < 8; ++j) acc[j] = 0.f;
#pragma unroll
  for (int k = 0; k < 3; ++k) {
    float ck = xT[k * BN + row];   // t=0
#pragma unroll
    for (int j = 0; j < 8; ++j) acc[j] += ck * gW[(64 + k) * 64 + u0 + j];
  }
  float esa = 0.f, eda = 0.f;
#pragma unroll
  for (int j = 0; j < 8; ++j) {
    esa += acc[j] * as_[u0 + j];
    eda += acc[j] * ad_[u0 + j];
  }
  f16x8 o;
#pragma unroll
  for (int j = 0; j < 8; ++j) o[j] = (f16_t)acc[j];
  *(f16x8*)(hp + (size_t)row * 64 + u0) = o;   // 16B store
  __shared__ float esL[8][64], edL[8][64];
  esL[wave][lane] = esa;
  edL[wave][lane] = eda;
  __syncthreads();
  if (wave == 0) {
    float s = 0.f;
#pragma unroll
    for (int w = 0; w < 8; ++w) s += esL[w][lane];
    es[row] = s;
  } else if (wave == 1) {
    float s = 0.f;
#pragma unroll
    for (int w = 0; w < 8; ++w) s += edL[w][lane];
    ed[row] = s;
  }
}

// R8: P1 gather reads f16 hp + u16 slot (halved L2 gather bytes; ~15us ->
// ~7.7us per-CU L2 floor). Rest as R7: MFMA GEMMs G1/G2/G3|G4.
// 512 thr, 8 waves, 64 rows/block, grid = 512.
__global__ __launch_bounds__(512, 4) void k_step(
    float* ws, const f16_t* P, const float* gb, const float* g1b,
    const float* g2b, const float* as_, const float* ad_,
    const float* ob, float* out, int t, int last) {
  const float* xT = ws + OFF_XT;
  int pr = t & 1;
  const f16_t* hpR = (const f16_t*)(ws + (pr ? OFF_HP1 : OFF_HP0));
  const float* esR = ws + (pr ? OFF_ES1 : OFF_ES0);
  const float* edR = ws + (pr ? OFF_ED1 : OFF_ED0);
  f16_t* hpW = (f16_t*)(ws + (pr ? OFF_HP0 : OFF_HP1));
  float* esW = ws + (pr ? OFF_ES0 : OFF_ES1);
  float* edW = ws + (pr ? OFF_ED0 : OFF_ED1);
  const int* cnt = (const int*)(ws + OFF_CNT);
  const unsigned short* slot = (const unsigned short*)(ws + OFF_SLOT);

  int tid = threadIdx.x;
  int wave = __builtin_amdgcn_readfirstlane(tid >> 6);  // 0..7
  int lane = tid & 63;
  int lb = xcd_remap(blockIdx.x);
  int rowbase = lb * 64;
  int b = rowbase / NN;
  int nbase = rowbase - b * NN;
  int r0 = wave * 8;

  __shared__ f16_t sx[64][104];    // A-tile: [s|x|0] -> later [h|x'|0]
  __shared__ f16_t rsx[64][104];   // A-tile: [r*s|x|0]
  __shared__ f16_t ugx[64][64];    // u gate
  __shared__ float peL[2][64], pdL[2][64];

  // tail fill k=64..95 of sx,rsx = [x(t) | zeros]
  for (int i = tid; i < 64 * 32; i += 512) {
    int row = i >> 5, kq = i & 31;
    f16_t v = (f16_t)0.f;
    if (kq < 3) v = (f16_t)xT[(t * 3 + kq) * BN + rowbase + row];
    sx[row][64 + kq] = v;
    rsx[row][64 + kq] = v;
  }

  float gbv = gb[lane];   // lane = u in P1

  // ---- P1: attention, 8 rows/wave (lane=u); write s -> sx f16 ----
#pragma unroll 1
  for (int rr = 0; rr < 8; ++rr) {
    int n = nbase + r0 + rr;
    int deg = min(cnt[n], CAP);
    float edv = edR[b * NN + n];
    int sl = (lane < deg) ? (int)slot[n * CAP + lane] : 0;
    float e = (lane < deg) ? (esR[b * NN + sl] + edv) : -1e30f;
    e = e > 0.f ? e : NEG * e;          // -1e30 -> exp = 0
    float w = __expf(e);                 // |e| <= ~8, no max-subtract needed
    float dsum = w;
#pragma unroll
    for (int o = 32; o >= 1; o >>= 1) dsum += __shfl_xor(dsum, o, 64);
    w *= 1.f / dsum;
    float acc = 0.f;
#pragma unroll 1
    for (int i0 = 0; i0 < deg; i0 += 8) {
#pragma unroll
      for (int j = 0; j < 8; ++j) {
        int idx = rli(sl, i0 + j);
        float wj = rlf(w, i0 + j);
        acc += wj * (float)hpR[(size_t)(b * NN + idx) * 64 + lane];
      }
    }
    sx[r0 + rr][lane] = (f16_t)(acc + gbv);
  }
  __syncthreads();

  const f16x8* W1v = (const f16x8*)(P + PW1);
  const f16x8* W2v = (const f16x8*)(P + PW2);
  const f16x8* W3v = (const f16x8*)(P + PW3);
  const f16x8* W4v = (const f16x8*)(P + PW4);

  int m = wave >> 1;               // C row-tile
  int col16 = lane & 15;
  int g4 = (lane >> 4) << 2;       // C row-group offset within tile
  int rbase = m * 16 + g4;         // + j = local row
  int afrow = m * 16 + col16;      // A-frag row (row = lane&15)
  int afk = (lane >> 4) << 3;      // A-frag k offset within kk-step

  // ---- G1: [s|x] @ g1W -> 64x128 (r | u pre-activations) ----
  int nb1 = (wave & 1) * 4;
  f32x4 acc1[4] = {{0,0,0,0},{0,0,0,0},{0,0,0,0},{0,0,0,0}};
#pragma unroll
  for (int kk = 0; kk < 3; ++kk) {
    f16x8 a = *(const f16x8*)&sx[afrow][kk * 32 + afk];
#pragma unroll
    for (int nt = 0; nt < 4; ++nt) {
      f16x8 bf = W1v[((nb1 + nt) * 3 + kk) * 64 + lane];
      acc1[nt] = __builtin_amdgcn_mfma_f32_16x16x32_f16(a, bf, acc1[nt], 0, 0, 0);
    }
  }
  if ((wave & 1) == 0) {           // r half: rs -> rsx
#pragma unroll
    for (int nt = 0; nt < 4; ++nt) {
      int colR = (nb1 + nt) * 16 + col16;
      float bR = g1b[colR];
#pragma unroll
      for (int j = 0; j < 4; ++j) {
        int row = rbase + j;
        float rg = 1.f / (1.f + __expf(-(acc1[nt][j] + bR)));
        rsx[row][colR] = (f16_t)(rg * (float)sx[row][colR]);
      }
    }
  } else {                          // u half: ug -> ugx
#pragma unroll
    for (int nt = 0; nt < 4; ++nt) {
      int colU = (nb1 - 4 + nt) * 16 + col16;
      float bU = g1b[64 + colU];
#pragma unroll
      for (int j = 0; j < 4; ++j) {
        int row = rbase + j;
        float ug = 1.f / (1.f + __expf(-(acc1[nt][j] + bU)));
        ugx[row][colU] = (f16_t)ug;
      }
    }
  }
  __syncthreads();

  // ---- G2: [rs|x] @ g2W -> candidate; h update in epilogue ----
  int nb2 = (wave & 1) * 2;
  f32x4 acc2[2] = {{0,0,0,0},{0,0,0,0}};
#pragma unroll
  for (int kk = 0; kk < 3; ++kk) {
    f16x8 a = *(const f16x8*)&rsx[afrow][kk * 32 + afk];
#pragma unroll
    for (int nt = 0; nt < 2; ++nt) {
      f16x8 bf = W2v[((nb2 + nt) * 3 + kk) * 64 + lane];
      acc2[nt] = __builtin_amdgcn_mfma_f32_16x16x32_f16(a, bf, acc2[nt], 0, 0, 0);
    }
  }
#pragma unroll
  for (int nt = 0; nt < 2; ++nt) {
    int col = (nb2 + nt) * 16 + col16;
    float bC = g2b[col];
#pragma unroll
    for (int j = 0; j < 4; ++j) {
      int row = rbase + j;
      float z = acc2[nt][j] + bC;
      float c = 1.f - 2.f / (__expf(2.f * z) + 1.f);
      float ug = (float)ugx[row][col];
      float sv = (float)sx[row][col];
      sx[row][col] = (f16_t)(ug * sv + (1.f - ug) * c);   // h (owner-only RMW)
    }
  }
  if (!last && tid < 256) {        // x(t) -> x(t+1) in sx tail
    int row = tid >> 2, k3 = tid & 3;
    if (k3 < 3)
      sx[row][64 + k3] = (f16_t)xT[((t + 1) * 3 + k3) * BN + rowbase + row];
  }
  __syncthreads();

  if (!last) {
    // ---- G3: [h|x'] @ gat_W -> hp' (f16) + es/ed ----
    int nb3 = (wave & 1) * 2;
    f32x4 acc3[2] = {{0,0,0,0},{0,0,0,0}};
#pragma unroll
    for (int kk = 0; kk < 3; ++kk) {
      f16x8 a = *(const f16x8*)&sx[afrow][kk * 32 + afk];
#pragma unroll
      for (int nt = 0; nt < 2; ++nt) {
        f16x8 bf = W3v[((nb3 + nt) * 3 + kk) * 64 + lane];
        acc3[nt] = __builtin_amdgcn_mfma_f32_16x16x32_f16(a, bf, acc3[nt], 0, 0, 0);
      }
    }
    float pe[4] = {0, 0, 0, 0}, pd[4] = {0, 0, 0, 0};
#pragma unroll
    for (int nt = 0; nt < 2; ++nt) {
      int col = (nb3 + nt) * 16 + col16;
      float asv = as_[col], adv = ad_[col];
#pragma unroll
      for (int j = 0; j < 4; ++j) {
        int row = rbase + j;
        float aG = acc3[nt][j];
        hpW[(size_t)(rowbase + row) * 64 + col] = (f16_t)aG;
        pe[j] += aG * asv;
        pd[j] += aG * adv;
      }
    }
#pragma unroll
    for (int j = 0; j < 4; ++j) {
#pragma unroll
      for (int o = 1; o < 16; o <<= 1) {
        pe[j] += __shfl_xor(pe[j], o, 64);
        pd[j] += __shfl_xor(pd[j], o, 64);
      }
    }
    if (col16 == 0) {
#pragma unroll
      for (int j = 0; j < 4; ++j) {
        peL[wave & 1][rbase + j] = pe[j];
        pdL[wave & 1][rbase + j] = pd[j];
      }
    }
    __syncthreads();
    if (tid < 64) {
      esW[rowbase + tid] = peL[0][tid] + peL[1][tid];
    } else if (tid < 128) {
      int r_ = tid - 64;
      edW[rowbase + r_] = pdL[0][r_] + pdL[1][r_];
    }
  } else {
    // ---- G4: out = h @ oW + ob (waves 0..3, 1 tile each) ----
    if (wave < 4) {
      f32x4 acc4 = {0, 0, 0, 0};
#pragma unroll
      for (int kk = 0; kk < 2; ++kk) {
        f16x8 a = *(const f16x8*)&sx[wave * 16 + col16][kk * 32 + afk];
        f16x8 bf = W4v[kk * 64 + lane];
        acc4 = __builtin_amdgcn_mfma_f32_16x16x32_f16(a, bf, acc4, 0, 0, 0);
      }
      if (col16 < 3) {
        float obv = ob[col16];
#pragma unroll
        for (int j = 0; j < 4; ++j) {
          int row = wave * 16 + g4 + j;
          out[(size_t)(rowbase + row) * 3 + col16] = acc4[j] + obv;
        }
      }
    }
  }
}

extern "C" void kernel_launch(void* const* d_in, const int* in_sizes, int n_in,
                              void* d_out, int out_size, void* d_ws, size_t ws_size,
                              hipStream_t stream) {
  const float* x = (const float*)d_in[0];
  const int* src = (const int*)d_in[1];
  const int* dst = (const int*)d_in[2];
  const float* gatW = (const float*)d_in[3];
  const float* asrc = (const float*)d_in[4];
  const float* adst = (const float*)d_in[5];
  const float* gatb = (const float*)d_in[6];
  const float* g1W = (const float*)d_in[7];
  const float* g1b = (const float*)d_in[8];
  const float* g2W = (const float*)d_in[9];
  const float* g2b = (const float*)d_in[10];
  const float* oW = (const float*)d_in[11];
  const float* ob = (const float*)d_in[12];
  float* ws = (float*)d_ws;
  float* out = (float*)d_out;
  f16_t* P = (f16_t*)(ws + OFF_W);

  hipMemsetAsync(ws + OFF_CNT, 0, NN * sizeof(int), stream);
  k_conv_x<<<(12 * BN) / 256, 256, 0, stream>>>(x, ws + OFF_XT);
  k_fill<<<(EE + NN) / 256, 256, 0, stream>>>(src, dst, (int*)(ws + OFF_CNT),
                                              (unsigned short*)(ws + OFF_SLOT));
  k_wpack<<<(NPANEL + 255) / 256, 256, 0, stream>>>(g1W, g2W, gatW, oW, P);
  k_gat0<<<BN / 64, 512, 0, stream>>>(ws, gatW, asrc, adst);
  for (int t = 0; t < TT; ++t) {
    k_step<<<BN / 64, 512, 0, stream>>>(ws, P, gatb, g1b, g2b, asrc, adst,
                                        ob, out, t, t == TT - 1 ? 1 : 0);
  }
}

// Round 9
// 187.319 us; speedup vs baseline: 1.6456x; 1.0492x over previous
//
#include <hip/hip_runtime.h>
#include <hip/hip_bf16.h>

#define BB 8
#define TT 4
#define NN 4096
#define UU 64
#define EE 65536
#define BN (BB*NN)   // 32768
#define CAP 64
#define NEG 0.2f

// ws layout (float offsets); hp/es/ed ping-pong by t parity.
// hp stored f16; slot u16.
#define OFF_XT   0                      // 12*BN  (t,f,row)
#define OFF_HP0  (12*BN)                // BN*64 f16 h' (region sized for f32; half used)
#define OFF_HP1  (OFF_HP0 + 64*BN)
#define OFF_ES0  (OFF_HP1 + 64*BN)     // BN
#define OFF_ES1  (OFF_ES0 + BN)
#define OFF_ED0  (OFF_ES1 + BN)
#define OFF_ED1  (OFF_ED0 + BN)
#define OFF_CNT  (OFF_ED1 + BN)        // NN ints
#define OFF_SLOT (OFF_CNT + NN)        // NN*CAP u16 (region sized for int; half used)
#define OFF_W    (OFF_SLOT + NN*CAP)   // f16 weight panels (frag-ordered)

// f16 panel offsets (in halfs). Element ((n*NKK+kk)*64+lane)*8+j holds
// W[k = kk*32 + (lane>>4)*8 + j][col = n*16 + (lane&15)] (zero-padded).
#define PW1 0          // G1: [s|x|0](96) @ g1W -> 128 cols; 8n x 3kk
#define PW2 12288      // G2: [rs|x|0](96) @ g2W -> 64 cols; 4n x 3kk
#define PW3 18432      // G3: [h|x'|0](96) @ gW  -> 64 cols; 4n x 3kk
#define PW4 24576      // G4: h(64) @ oW -> 16 cols (3 used); 1n x 2kk
#define NPANEL 25600

// prologue sub-grid bounds (256-thr blocks)
#define PB_CONV 1536   // 12*BN/256
#define PB_FILL 272    // (EE+NN)/256
#define PB_PACK 100    // NPANEL/256

typedef _Float16 f16_t;
typedef _Float16 f16x8 __attribute__((ext_vector_type(8)));
typedef float f32x4 __attribute__((ext_vector_type(4)));

// XCD-aware block remap: pin batch i to XCD i (R2: FETCH 42.9->7.4 MB; keep).
__device__ __forceinline__ int xcd_remap(int bid) {
  return ((bid & 7) << 6) | (bid >> 3);
}

// readlane helpers: VALU broadcast -> SGPR.
__device__ __forceinline__ float rlf(float v, int l) {
  return __int_as_float(__builtin_amdgcn_readlane(__float_as_int(v), l));
}
__device__ __forceinline__ int rli(int v, int l) {
  return __builtin_amdgcn_readlane(v, l);
}

// R9: merged prologue = conv_x | fill | wpack (disjoint ws regions).
__global__ __launch_bounds__(256) void k_prolog(const float* x, const int* src,
                                                const int* dst, const float* g1W,
                                                const float* g2W, const float* gW,
                                                const float* oW, float* ws) {
  int bid = blockIdx.x;
  int tid = threadIdx.x;
  if (bid < PB_CONV) {
    // transpose x -> xT[(t,f,row)]
    int i = bid * 256 + tid;
    int r = i & (BN - 1);
    int tf = i >> 15;
    int t = tf / 3, f = tf - 3 * t;
    int b = r >> 12, n = r & (NN - 1);
    ws[OFF_XT + i] = x[(((b * TT + t) * NN + n) * 3) + f];
  } else if (bid < PB_CONV + PB_FILL) {
    // CSR-ish slot fill (cnt memset'd before this kernel)
    int* cnt = (int*)(ws + OFF_CNT);
    unsigned short* slot = (unsigned short*)(ws + OFF_SLOT);
    int i = (bid - PB_CONV) * 256 + tid;
    if (i < EE) {
      int d = dst[i];
      int p = atomicAdd(&cnt[d], 1);
      if (p < CAP) slot[d * CAP + p] = (unsigned short)src[i];
    } else {
      int n = i - EE;
      int p = atomicAdd(&cnt[n], 1);
      if (p < CAP) slot[n * CAP + p] = (unsigned short)n;
    }
  } else {
    // pack f32 weights into frag-ordered f16 panels
    f16_t* P = (f16_t*)(ws + OFF_W);
    int i = (bid - PB_CONV - PB_FILL) * 256 + tid;
    if (i >= NPANEL) return;
    int j = i & 7;
    int l = (i >> 3) & 63;
    int kap = ((l >> 4) << 3) + j;
    float v = 0.f;
    if (i < PW2) {
      int r = i >> 9;
      int kk = r % 3, n = r / 3;
      int k = kk * 32 + kap, col = n * 16 + (l & 15);
      if (k < 64) v = g1W[(3 + k) * 128 + col];
      else if (k < 67) v = g1W[(k - 64) * 128 + col];
    } else if (i < PW3) {
      int r = (i - PW2) >> 9;
      int kk = r % 3, n = r / 3;
      int k = kk * 32 + kap, col = n * 16 + (l & 15);
      if (k < 64) v = g2W[(3 + k) * 64 + col];
      else if (k < 67) v = g2W[(k - 64) * 64 + col];
    } else if (i < PW4) {
      int r = (i - PW3) >> 9;
      int kk = r % 3, n = r / 3;
      int k = kk * 32 + kap, col = n * 16 + (l & 15);
      if (k < 67) v = gW[k * 64 + col];
    } else {
      int kk = (i - PW4) >> 9;
      int k = kk * 32 + kap, col = l & 15;
      if (col < 3) v = oW[k * 3 + col];
    }
    P[i] = (f16_t)v;
  }
}

// GAT at t=0 (h == 0): h' = x_0 @ gat_W[64:67]; es/ed. Writes buffer 0 (f16 hp).
__global__ __launch_bounds__(512) void k_gat0(float* ws, const float* gW,
                                              const float* as_, const float* ad_) {
  const float* xT = ws + OFF_XT;
  f16_t* hp = (f16_t*)(ws + OFF_HP0);
  float* es = ws + OFF_ES0;
  float* ed = ws + OFF_ED0;
  int wave = __builtin_amdgcn_readfirstlane(threadIdx.x >> 6);
  int lane = threadIdx.x & 63;
  int lb = xcd_remap(blockIdx.x);
  int row = lb * 64 + lane;
  int u0 = wave * 8;
  float acc[8];
#pragma unroll
  for (int j = 0; j < 8; ++j) acc[j] = 0.f;
#pragma unroll
  for (int k = 0; k < 3; ++k) {
    float ck = xT[k * BN + row];   // t=0
#pragma unroll
    for (int j = 0; j < 8; ++j) acc[j] += ck * gW[(64 + k) * 64 + u0 + j];
  }
  float esa = 0.f, eda = 0.f;
#pragma unroll
  for (int j = 0; j < 8; ++j) {
    esa += acc[j] * as_[u0 + j];
    eda += acc[j] * ad_[u0 + j];
  }
  f16x8 o;
#pragma unroll
  for (int j = 0; j < 8; ++j) o[j] = (f16_t)acc[j];
  *(f16x8*)(hp + (size_t)row * 64 + u0) = o;   // 16B store
  __shared__ float esL[8][64], edL[8][64];
  esL[wave][lane] = esa;
  edL[wave][lane] = eda;
  __syncthreads();
  if (wave == 0) {
    float s = 0.f;
#pragma unroll
    for (int w = 0; w < 8; ++w) s += esL[w][lane];
    es[row] = s;
  } else if (wave == 1) {
    float s = 0.f;
#pragma unroll
    for (int w = 0; w < 8; ++w) s += edL[w][lane];
    ed[row] = s;
  }
}

// R9: P1 software-pipelined (batch loads for 8 rows; gather 2 rows interleaved,
// 16 loads in flight). Rest as R8: MFMA GEMMs G1/G2/G3|G4.
// 512 thr, 8 waves, 64 rows/block, grid = 512.
__global__ __launch_bounds__(512, 4) void k_step(
    float* ws, const f16_t* P, const float* gb, const float* g1b,
    const float* g2b, const float* as_, const float* ad_,
    const float* ob, float* out, int t, int last) {
  const float* xT = ws + OFF_XT;
  int pr = t & 1;
  const f16_t* hpR = (const f16_t*)(ws + (pr ? OFF_HP1 : OFF_HP0));
  const float* esR = ws + (pr ? OFF_ES1 : OFF_ES0);
  const float* edR = ws + (pr ? OFF_ED1 : OFF_ED0);
  f16_t* hpW = (f16_t*)(ws + (pr ? OFF_HP0 : OFF_HP1));
  float* esW = ws + (pr ? OFF_ES0 : OFF_ES1);
  float* edW = ws + (pr ? OFF_ED0 : OFF_ED1);
  const int* cnt = (const int*)(ws + OFF_CNT);
  const unsigned short* slot = (const unsigned short*)(ws + OFF_SLOT);

  int tid = threadIdx.x;
  int wave = __builtin_amdgcn_readfirstlane(tid >> 6);  // 0..7
  int lane = tid & 63;
  int lb = xcd_remap(blockIdx.x);
  int rowbase = lb * 64;
  int b = rowbase / NN;
  int nbase = rowbase - b * NN;
  int r0 = wave * 8;

  __shared__ f16_t sx[64][104];    // A-tile: [s|x|0] -> later [h|x'|0]
  __shared__ f16_t rsx[64][104];   // A-tile: [r*s|x|0]
  __shared__ f16_t ugx[64][64];    // u gate
  __shared__ float peL[2][64], pdL[2][64];

  // tail fill k=64..95 of sx,rsx = [x(t) | zeros]
  for (int i = tid; i < 64 * 32; i += 512) {
    int row = i >> 5, kq = i & 31;
    f16_t v = (f16_t)0.f;
    if (kq < 3) v = (f16_t)xT[(t * 3 + kq) * BN + rowbase + row];
    sx[row][64 + kq] = v;
    rsx[row][64 + kq] = v;
  }

  float gbv = gb[lane];   // lane = u in P1

  // ---- P1 (pipelined): batch scalar loads for all 8 rows ----
  int deg8[8]; float ed8[8];
#pragma unroll
  for (int rr = 0; rr < 8; ++rr) {
    int n = nbase + r0 + rr;
    deg8[rr] = min(cnt[n], CAP);
    ed8[rr] = edR[b * NN + n];
  }
  int sl8[8];
#pragma unroll
  for (int rr = 0; rr < 8; ++rr) {
    int n = nbase + r0 + rr;
    int sv = (int)slot[n * CAP + lane];
    sl8[rr] = (lane < deg8[rr]) ? sv : 0;   // masked -> row 0 (finite), w=0
  }
  float w8[8];
#pragma unroll
  for (int rr = 0; rr < 8; ++rr) {
    float ev = esR[b * NN + sl8[rr]];       // 8 gathers in flight
    float e = (lane < deg8[rr]) ? (ev + ed8[rr]) : -1e30f;
    e = e > 0.f ? e : NEG * e;              // -1e30 -> exp underflows to 0
    w8[rr] = __expf(e);
  }
#pragma unroll
  for (int rr = 0; rr < 8; ++rr) {
    float dsum = w8[rr];
#pragma unroll
    for (int o = 32; o >= 1; o >>= 1) dsum += __shfl_xor(dsum, o, 64);
    w8[rr] *= 1.f / dsum;
  }
  // weighted gather, 2 rows interleaved (16 loads in flight)
  const f16_t* hpB = hpR + (size_t)b * NN * 64;
#pragma unroll
  for (int rp = 0; rp < 8; rp += 2) {
    float accA = 0.f, accB = 0.f;
    int dA = deg8[rp], dB = deg8[rp + 1];
    int dm = dA > dB ? dA : dB;
#pragma unroll 1
    for (int i0 = 0; i0 < dm; i0 += 8) {
      float vA[8], vB[8];
#pragma unroll
      for (int j = 0; j < 8; ++j) {
        vA[j] = (float)hpB[(size_t)rli(sl8[rp], i0 + j) * 64 + lane];
        vB[j] = (float)hpB[(size_t)rli(sl8[rp + 1], i0 + j) * 64 + lane];
      }
#pragma unroll
      for (int j = 0; j < 8; ++j) {
        accA += rlf(w8[rp], i0 + j) * vA[j];     // w==0 beyond deg
        accB += rlf(w8[rp + 1], i0 + j) * vB[j];
      }
    }
    sx[r0 + rp][lane] = (f16_t)(accA + gbv);
    sx[r0 + rp + 1][lane] = (f16_t)(accB + gbv);
  }
  __syncthreads();

  const f16x8* W1v = (const f16x8*)(P + PW1);
  const f16x8* W2v = (const f16x8*)(P + PW2);
  const f16x8* W3v = (const f16x8*)(P + PW3);
  const f16x8* W4v = (const f16x8*)(P + PW4);

  int m = wave >> 1;               // C row-tile
  int col16 = lane & 15;
  int g4 = (lane >> 4) << 2;       // C row-group offset within tile
  int rbase = m * 16 + g4;         // + j = local row
  int afrow = m * 16 + col16;      // A-frag row (row = lane&15)
  int afk = (lane >> 4) << 3;      // A-frag k offset within kk-step

  // ---- G1: [s|x] @ g1W -> 64x128 (r | u pre-activations) ----
  int nb1 = (wave & 1) * 4;
  f32x4 acc1[4] = {{0,0,0,0},{0,0,0,0},{0,0,0,0},{0,0,0,0}};
#pragma unroll
  for (int kk = 0; kk < 3; ++kk) {
    f16x8 a = *(const f16x8*)&sx[afrow][kk * 32 + afk];
#pragma unroll
    for (int nt = 0; nt < 4; ++nt) {
      f16x8 bf = W1v[((nb1 + nt) * 3 + kk) * 64 + lane];
      acc1[nt] = __builtin_amdgcn_mfma_f32_16x16x32_f16(a, bf, acc1[nt], 0, 0, 0);
    }
  }
  if ((wave & 1) == 0) {           // r half: rs -> rsx
#pragma unroll
    for (int nt = 0; nt < 4; ++nt) {
      int colR = (nb1 + nt) * 16 + col16;
      float bR = g1b[colR];
#pragma unroll
      for (int j = 0; j < 4; ++j) {
        int row = rbase + j;
        float rg = 1.f / (1.f + __expf(-(acc1[nt][j] + bR)));
        rsx[row][colR] = (f16_t)(rg * (float)sx[row][colR]);
      }
    }
  } else {                          // u half: ug -> ugx
#pragma unroll
    for (int nt = 0; nt < 4; ++nt) {
      int colU = (nb1 - 4 + nt) * 16 + col16;
      float bU = g1b[64 + colU];
#pragma unroll
      for (int j = 0; j < 4; ++j) {
        int row = rbase + j;
        float ug = 1.f / (1.f + __expf(-(acc1[nt][j] + bU)));
        ugx[row][colU] = (f16_t)ug;
      }
    }
  }
  __syncthreads();

  // ---- G2: [rs|x] @ g2W -> candidate; h update in epilogue ----
  int nb2 = (wave & 1) * 2;
  f32x4 acc2[2] = {{0,0,0,0},{0,0,0,0}};
#pragma unroll
  for (int kk = 0; kk < 3; ++kk) {
    f16x8 a = *(const f16x8*)&rsx[afrow][kk * 32 + afk];
#pragma unroll
    for (int nt = 0; nt < 2; ++nt) {
      f16x8 bf = W2v[((nb2 + nt) * 3 + kk) * 64 + lane];
      acc2[nt] = __builtin_amdgcn_mfma_f32_16x16x32_f16(a, bf, acc2[nt], 0, 0, 0);
    }
  }
#pragma unroll
  for (int nt = 0; nt < 2; ++nt) {
    int col = (nb2 + nt) * 16 + col16;
    float bC = g2b[col];
#pragma unroll
    for (int j = 0; j < 4; ++j) {
      int row = rbase + j;
      float z = acc2[nt][j] + bC;
      float c = 1.f - 2.f / (__expf(2.f * z) + 1.f);
      float ug = (float)ugx[row][col];
      float sv = (float)sx[row][col];
      sx[row][col] = (f16_t)(ug * sv + (1.f - ug) * c);   // h (owner-only RMW)
    }
  }
  if (!last && tid < 256) {        // x(t) -> x(t+1) in sx tail
    int row = tid >> 2, k3 = tid & 3;
    if (k3 < 3)
      sx[row][64 + k3] = (f16_t)xT[((t + 1) * 3 + k3) * BN + rowbase + row];
  }
  __syncthreads();

  if (!last) {
    // ---- G3: [h|x'] @ gat_W -> hp' (f16) + es/ed ----
    int nb3 = (wave & 1) * 2;
    f32x4 acc3[2] = {{0,0,0,0},{0,0,0,0}};
#pragma unroll
    for (int kk = 0; kk < 3; ++kk) {
      f16x8 a = *(const f16x8*)&sx[afrow][kk * 32 + afk];
#pragma unroll
      for (int nt = 0; nt < 2; ++nt) {
        f16x8 bf = W3v[((nb3 + nt) * 3 + kk) * 64 + lane];
        acc3[nt] = __builtin_amdgcn_mfma_f32_16x16x32_f16(a, bf, acc3[nt], 0, 0, 0);
      }
    }
    float pe[4] = {0, 0, 0, 0}, pd[4] = {0, 0, 0, 0};
#pragma unroll
    for (int nt = 0; nt < 2; ++nt) {
      int col = (nb3 + nt) * 16 + col16;
      float asv = as_[col], adv = ad_[col];
#pragma unroll
      for (int j = 0; j < 4; ++j) {
        int row = rbase + j;
        float aG = acc3[nt][j];
        hpW[(size_t)(rowbase + row) * 64 + col] = (f16_t)aG;
        pe[j] += aG * asv;
        pd[j] += aG * adv;
      }
    }
#pragma unroll
    for (int j = 0; j < 4; ++j) {
#pragma unroll
      for (int o = 1; o < 16; o <<= 1) {
        pe[j] += __shfl_xor(pe[j], o, 64);
        pd[j] += __shfl_xor(pd[j], o, 64);
      }
    }
    if (col16 == 0) {
#pragma unroll
      for (int j = 0; j < 4; ++j) {
        peL[wave & 1][rbase + j] = pe[j];
        pdL[wave & 1][rbase + j] = pd[j];
      }
    }
    __syncthreads();
    if (tid < 64) {
      esW[rowbase + tid] = peL[0][tid] + peL[1][tid];
    } else if (tid < 128) {
      int r_ = tid - 64;
      edW[rowbase + r_] = pdL[0][r_] + pdL[1][r_];
    }
  } else {
    // ---- G4: out = h @ oW + ob (waves 0..3, 1 tile each) ----
    if (wave < 4) {
      f32x4 acc4 = {0, 0, 0, 0};
#pragma unroll
      for (int kk = 0; kk < 2; ++kk) {
        f16x8 a = *(const f16x8*)&sx[wave * 16 + col16][kk * 32 + afk];
        f16x8 bf = W4v[kk * 64 + lane];
        acc4 = __builtin_amdgcn_mfma_f32_16x16x32_f16(a, bf, acc4, 0, 0, 0);
      }
      if (col16 < 3) {
        float obv = ob[col16];
#pragma unroll
        for (int j = 0; j < 4; ++j) {
          int row = wave * 16 + g4 + j;
          out[(size_t)(rowbase + row) * 3 + col16] = acc4[j] + obv;
        }
      }
    }
  }
}

extern "C" void kernel_launch(void* const* d_in, const int* in_sizes, int n_in,
                              void* d_out, int out_size, void* d_ws, size_t ws_size,
                              hipStream_t stream) {
  const float* x = (const float*)d_in[0];
  const int* src = (const int*)d_in[1];
  const int* dst = (const int*)d_in[2];
  const float* gatW = (const float*)d_in[3];
  const float* asrc = (const float*)d_in[4];
  const float* adst = (const float*)d_in[5];
  const float* gatb = (const float*)d_in[6];
  const float* g1W = (const float*)d_in[7];
  const float* g1b = (const float*)d_in[8];
  const float* g2W = (const float*)d_in[9];
  const float* g2b = (const float*)d_in[10];
  const float* oW = (const float*)d_in[11];
  const float* ob = (const float*)d_in[12];
  float* ws = (float*)d_ws;
  float* out = (float*)d_out;
  f16_t* P = (f16_t*)(ws + OFF_W);

  hipMemsetAsync(ws + OFF_CNT, 0, NN * sizeof(int), stream);
  k_prolog<<<PB_CONV + PB_FILL + PB_PACK, 256, 0, stream>>>(x, src, dst, g1W,
                                                            g2W, gatW, oW, ws);
  k_gat0<<<BN / 64, 512, 0, stream>>>(ws, gatW, asrc, adst);
  for (int t = 0; t < TT; ++t) {
    k_step<<<BN / 64, 512, 0, stream>>>(ws, P, gatb, g1b, g2b, asrc, adst,
                                        ob, out, t, t == TT - 1 ? 1 : 0);
  }
}